// Round 2
// baseline (42874.606 us; speedup 1.0000x reference)
//
#include <hip/hip_runtime.h>

#define NS 1024
#define NH 64
#define NB 16384

// ---- XLA-CPU fp32 op clones (no FP contraction: __fmul_rn/__fadd_rn) ----

// Clone of XLA GenerateVF32Exp (Cephes/Eigen pexp, as in llvm_ir_runtime.cc)
__device__ __forceinline__ float xexp(float x) {
  x = fminf(x, 88.3762626647950f);
  x = fmaxf(x, -88.3762626647949f);
  float fx = floorf(__fadd_rn(__fmul_rn(x, 1.44269504088896341f), 0.5f));
  x = __fsub_rn(x, __fmul_rn(fx, 0.693359375f));
  x = __fsub_rn(x, __fmul_rn(fx, -2.12194440e-4f));
  float z = __fmul_rn(x, x);
  float y = 1.9875691500e-4f;
  y = __fadd_rn(__fmul_rn(y, x), 1.3981999507e-3f);
  y = __fadd_rn(__fmul_rn(y, x), 8.3334519073e-3f);
  y = __fadd_rn(__fmul_rn(y, x), 4.1665795894e-2f);
  y = __fadd_rn(__fmul_rn(y, x), 1.6666665459e-1f);
  y = __fadd_rn(__fmul_rn(y, x), 5.0000001201e-1f);
  y = __fadd_rn(__fmul_rn(y, z), x);
  y = __fadd_rn(y, 1.0f);
  int n = (int)fx;
  float p2n = __int_as_float((n + 127) << 23);
  return __fmul_rn(y, p2n);
}

// XLA logistic expansion: 1 / (1 + exp(-x)), IEEE divide
__device__ __forceinline__ float xsigmoid(float x) {
  float e = xexp(-x);
  return __fdiv_rn(1.0f, __fadd_rn(1.0f, e));
}

// Clone of XLA EmitFastTanh (Eigen ptanh rational approximation)
__device__ __forceinline__ float xtanh(float x) {
  float xc = fminf(fmaxf(x, -7.90531110763549805f), 7.90531110763549805f);
  float s = __fmul_rn(xc, xc);
  float p = -2.76076847742355e-16f;
  p = __fadd_rn(__fmul_rn(p, s), 2.00018790482477e-13f);
  p = __fadd_rn(__fmul_rn(p, s), -8.60467152213735e-11f);
  p = __fadd_rn(__fmul_rn(p, s), 5.12229709037114e-08f);
  p = __fadd_rn(__fmul_rn(p, s), 1.48572235717979e-05f);
  p = __fadd_rn(__fmul_rn(p, s), 6.37261928875436e-04f);
  p = __fadd_rn(__fmul_rn(p, s), 4.89352455891786e-03f);
  float num = __fmul_rn(xc, p);
  float q = 1.19825839466702e-06f;
  q = __fadd_rn(__fmul_rn(q, s), 1.18534705686654e-04f);
  q = __fadd_rn(__fmul_rn(q, s), 2.26843463243900e-03f);
  q = __fadd_rn(__fmul_rn(q, s), 4.89352518554385e-03f);
  float rat = __fdiv_rn(num, q);
  return (fabsf(x) < 0.0004f) ? x : rat;
}

// Two rows per wave: lane j owns hidden unit j for BOTH rows; the 192
// weight floats (registers) are shared, amortizing AGPR traffic and giving
// two independent chains of ILP. Wave-uniform head sigmoid is packed:
// lanes 0-31 evaluate row A's logit, lanes 32-63 row B's.
__global__ __launch_bounds__(256, 2) void gru_sample_kernel(
    const float* __restrict__ u, const float* __restrict__ w_ih,
    const float* __restrict__ w_hh, const float* __restrict__ b_ih,
    const float* __restrict__ b_hh, const float* __restrict__ head_w,
    const float* __restrict__ head_b, int* __restrict__ out) {
  const int lane = threadIdx.x & 63;
  const int wv = threadIdx.x >> 6;
  const int rowA = blockIdx.x * 8 + wv * 2;
  const int rowB = rowA + 1;

  __shared__ float hbuf[8][NH];
  float* hbA = hbuf[wv * 2];
  float* hbB = hbuf[wv * 2 + 1];

  // Per-lane weight rows: w_hh[(g*64+lane)][k], k = 0..63 (shared by A,B)
  float w_r[NH], w_z[NH], w_n[NH];
#pragma unroll
  for (int kq = 0; kq < 16; ++kq) {
    float4 a = *(const float4*)&w_hh[(size_t)(lane)*NH + kq * 4];
    float4 b = *(const float4*)&w_hh[(size_t)(64 + lane) * NH + kq * 4];
    float4 c = *(const float4*)&w_hh[(size_t)(128 + lane) * NH + kq * 4];
    w_r[kq * 4 + 0] = a.x; w_r[kq * 4 + 1] = a.y; w_r[kq * 4 + 2] = a.z; w_r[kq * 4 + 3] = a.w;
    w_z[kq * 4 + 0] = b.x; w_z[kq * 4 + 1] = b.y; w_z[kq * 4 + 2] = b.z; w_z[kq * 4 + 3] = b.w;
    w_n[kq * 4 + 0] = c.x; w_n[kq * 4 + 1] = c.y; w_n[kq * 4 + 2] = c.z; w_n[kq * 4 + 3] = c.w;
  }
  const float bih_r = b_ih[lane], bih_z = b_ih[64 + lane], bih_n = b_ih[128 + lane];
  const float bhh_r = b_hh[lane], bhh_z = b_hh[64 + lane], bhh_n = b_hh[128 + lane];
  // prev ∈ {0,1}: gx = prev*w_ih + b_ih == (prev ? w_ih+b_ih : b_ih) bit-exactly.
  const float sum_r = __fadd_rn(w_ih[lane], bih_r);
  const float sum_z = __fadd_rn(w_ih[64 + lane], bih_z);
  const float sum_n = __fadd_rn(w_ih[128 + lane], bih_n);
  const float hw = head_w[lane];
  const float hb = head_b[0];

  const float* urA = u + (size_t)rowA * NS;
  const float* urB = u + (size_t)rowB * NS;
  int* orA = out + (size_t)rowA * NS;
  int* orB = out + (size_t)rowB * NS;

  float hA = 0.0f, hB = 0.0f;
  int prevA = 0, prevB = 0;
  hbA[lane] = 0.0f;
  hbB[lane] = 0.0f;

  float uA_cur = urA[lane];
  float uB_cur = urB[lane];
  for (int c = 0; c < 16; ++c) {
    float uA_next = (c < 15) ? urA[(c + 1) * 64 + lane] : 0.0f;
    float uB_next = (c < 15) ? urB[(c + 1) * 64 + lane] : 0.0f;
    int mybitA = 0, mybitB = 0;
    for (int tt = 0; tt < 64; ++tt) {
      // gh = h @ w_hh.T for both rows: sequential-k FMA from 0 (Eigen gebp)
      float arA = 0.0f, azA = 0.0f, anA = 0.0f;
      float arB = 0.0f, azB = 0.0f, anB = 0.0f;
#pragma unroll
      for (int kq = 0; kq < 16; ++kq) {
        float4 hvA = *(const float4*)&hbA[kq * 4];
        float4 hvB = *(const float4*)&hbB[kq * 4];
        float w0 = w_r[kq * 4 + 0], w1 = w_r[kq * 4 + 1], w2 = w_r[kq * 4 + 2], w3 = w_r[kq * 4 + 3];
        arA = fmaf(hvA.x, w0, arA); arB = fmaf(hvB.x, w0, arB);
        arA = fmaf(hvA.y, w1, arA); arB = fmaf(hvB.y, w1, arB);
        arA = fmaf(hvA.z, w2, arA); arB = fmaf(hvB.z, w2, arB);
        arA = fmaf(hvA.w, w3, arA); arB = fmaf(hvB.w, w3, arB);
        w0 = w_z[kq * 4 + 0]; w1 = w_z[kq * 4 + 1]; w2 = w_z[kq * 4 + 2]; w3 = w_z[kq * 4 + 3];
        azA = fmaf(hvA.x, w0, azA); azB = fmaf(hvB.x, w0, azB);
        azA = fmaf(hvA.y, w1, azA); azB = fmaf(hvB.y, w1, azB);
        azA = fmaf(hvA.z, w2, azA); azB = fmaf(hvB.z, w2, azB);
        azA = fmaf(hvA.w, w3, azA); azB = fmaf(hvB.w, w3, azB);
        w0 = w_n[kq * 4 + 0]; w1 = w_n[kq * 4 + 1]; w2 = w_n[kq * 4 + 2]; w3 = w_n[kq * 4 + 3];
        anA = fmaf(hvA.x, w0, anA); anB = fmaf(hvB.x, w0, anB);
        anA = fmaf(hvA.y, w1, anA); anB = fmaf(hvB.y, w1, anB);
        anA = fmaf(hvA.z, w2, anA); anB = fmaf(hvB.z, w2, anB);
        anA = fmaf(hvA.w, w3, anA); anB = fmaf(hvB.w, w3, anB);
      }
      // gates, exact reference association
      float ghnA = __fadd_rn(anA, bhh_n);
      float ghnB = __fadd_rn(anB, bhh_n);
      float rA = xsigmoid(__fadd_rn(prevA ? sum_r : bih_r, __fadd_rn(arA, bhh_r)));
      float rB = xsigmoid(__fadd_rn(prevB ? sum_r : bih_r, __fadd_rn(arB, bhh_r)));
      float zA = xsigmoid(__fadd_rn(prevA ? sum_z : bih_z, __fadd_rn(azA, bhh_z)));
      float zB = xsigmoid(__fadd_rn(prevB ? sum_z : bih_z, __fadd_rn(azB, bhh_z)));
      float nA = xtanh(__fadd_rn(prevA ? sum_n : bih_n, __fmul_rn(rA, ghnA)));
      float nB = xtanh(__fadd_rn(prevB ? sum_n : bih_n, __fmul_rn(rB, ghnB)));
      hA = __fadd_rn(__fmul_rn(__fsub_rn(1.0f, zA), nA), __fmul_rn(zA, hA));
      hB = __fadd_rn(__fmul_rn(__fsub_rn(1.0f, zB), nB), __fmul_rn(zB, hB));
      hbA[lane] = hA;
      hbB[lane] = hB;

      // head gemv clone per row: width-16 chunks then halving tree
      float PA = __fmul_rn(hA, hw);
      float PB = __fmul_rn(hB, hw);
      float sA = __fadd_rn(PA, __shfl(PA, lane + 16));
      float sB = __fadd_rn(PB, __shfl(PB, lane + 16));
      sA = __fadd_rn(sA, __shfl(PA, lane + 32));
      sB = __fadd_rn(sB, __shfl(PB, lane + 32));
      sA = __fadd_rn(sA, __shfl(PA, lane + 48));
      sB = __fadd_rn(sB, __shfl(PB, lane + 48));
      sA = __fadd_rn(sA, __shfl(sA, lane + 8));
      sB = __fadd_rn(sB, __shfl(sB, lane + 8));
      sA = __fadd_rn(sA, __shfl(sA, lane + 4));
      sB = __fadd_rn(sB, __shfl(sB, lane + 4));
      sA = __fadd_rn(sA, __shfl(sA, lane + 2));
      sB = __fadd_rn(sB, __shfl(sB, lane + 2));
      sA = __fadd_rn(sA, __shfl(sA, lane + 1));
      sB = __fadd_rn(sB, __shfl(sB, lane + 1));
      float logitA = __fadd_rn(__shfl(sA, 0), hb);
      float logitB = __fadd_rn(__shfl(sB, 0), hb);

      // packed head sigmoid: one instruction stream serves both rows
      float lg = (lane < 32) ? logitA : logitB;
      float pp = xsigmoid(lg);
      float pA = __shfl(pp, 0);
      float pB = __shfl(pp, 32);

      float uAt = __shfl(uA_cur, tt);
      float uBt = __shfl(uB_cur, tt);
      int bA = (uAt < pA) ? 1 : 0;
      int bB = (uBt < pB) ? 1 : 0;
      prevA = bA;
      prevB = bB;
      mybitA = (lane == tt) ? bA : mybitA;
      mybitB = (lane == tt) ? bB : mybitB;
    }
    orA[c * 64 + lane] = mybitA;
    orB[c * 64 + lane] = mybitB;
    uA_cur = uA_next;
    uB_cur = uB_next;
  }
}

extern "C" void kernel_launch(void* const* d_in, const int* in_sizes, int n_in,
                              void* d_out, int out_size, void* d_ws, size_t ws_size,
                              hipStream_t stream) {
  const float* u = (const float*)d_in[0];
  const float* w_ih = (const float*)d_in[1];
  const float* w_hh = (const float*)d_in[2];
  const float* b_ih = (const float*)d_in[3];
  const float* b_hh = (const float*)d_in[4];
  const float* head_w = (const float*)d_in[5];
  const float* head_b = (const float*)d_in[6];
  int* out = (int*)d_out;
  dim3 grid(NB / 8), block(256);
  gru_sample_kernel<<<grid, block, 0, stream>>>(u, w_ih, w_hh, b_ih, b_hh,
                                                head_w, head_b, out);
}

// Round 3
// 16025.258 us; speedup vs baseline: 2.6754x; 2.6754x over previous
//
#include <hip/hip_runtime.h>

#define NS 1024
#define NH 64
#define NB 16384

// ---- XLA-CPU fp32 op clones (no FP contraction: __fmul_rn/__fadd_rn) ----

// Clone of XLA GenerateVF32Exp (Cephes/Eigen pexp, as in llvm_ir_runtime.cc)
__device__ __forceinline__ float xexp(float x) {
  x = fminf(x, 88.3762626647950f);
  x = fmaxf(x, -88.3762626647949f);
  float fx = floorf(__fadd_rn(__fmul_rn(x, 1.44269504088896341f), 0.5f));
  x = __fsub_rn(x, __fmul_rn(fx, 0.693359375f));
  x = __fsub_rn(x, __fmul_rn(fx, -2.12194440e-4f));
  float z = __fmul_rn(x, x);
  float y = 1.9875691500e-4f;
  y = __fadd_rn(__fmul_rn(y, x), 1.3981999507e-3f);
  y = __fadd_rn(__fmul_rn(y, x), 8.3334519073e-3f);
  y = __fadd_rn(__fmul_rn(y, x), 4.1665795894e-2f);
  y = __fadd_rn(__fmul_rn(y, x), 1.6666665459e-1f);
  y = __fadd_rn(__fmul_rn(y, x), 5.0000001201e-1f);
  y = __fadd_rn(__fmul_rn(y, z), x);
  y = __fadd_rn(y, 1.0f);
  int n = (int)fx;
  float p2n = __int_as_float((n + 127) << 23);
  return __fmul_rn(y, p2n);
}

// XLA logistic expansion: 1 / (1 + exp(-x)), IEEE divide
__device__ __forceinline__ float xsigmoid(float x) {
  float e = xexp(-x);
  return __fdiv_rn(1.0f, __fadd_rn(1.0f, e));
}

// Clone of XLA EmitFastTanh (Eigen ptanh rational approximation)
__device__ __forceinline__ float xtanh(float x) {
  float xc = fminf(fmaxf(x, -7.90531110763549805f), 7.90531110763549805f);
  float s = __fmul_rn(xc, xc);
  float p = -2.76076847742355e-16f;
  p = __fadd_rn(__fmul_rn(p, s), 2.00018790482477e-13f);
  p = __fadd_rn(__fmul_rn(p, s), -8.60467152213735e-11f);
  p = __fadd_rn(__fmul_rn(p, s), 5.12229709037114e-08f);
  p = __fadd_rn(__fmul_rn(p, s), 1.48572235717979e-05f);
  p = __fadd_rn(__fmul_rn(p, s), 6.37261928875436e-04f);
  p = __fadd_rn(__fmul_rn(p, s), 4.89352455891786e-03f);
  float num = __fmul_rn(xc, p);
  float q = 1.19825839466702e-06f;
  q = __fadd_rn(__fmul_rn(q, s), 1.18534705686654e-04f);
  q = __fadd_rn(__fmul_rn(q, s), 2.26843463243900e-03f);
  q = __fadd_rn(__fmul_rn(q, s), 4.89352518554385e-03f);
  float rat = __fdiv_rn(num, q);
  return (fabsf(x) < 0.0004f) ? x : rat;
}

// ONE wave per block (64 threads), TWO rows per wave. Lane j owns hidden
// unit j for both rows; the 192 shared weight floats live in the unified
// 256V+256A register file (no spill: launch_bounds(64,1) lifts the
// 128-VGPR cap that caused round-2's 73 GB scratch thrash).
__global__ __launch_bounds__(64, 1) void gru_sample_kernel(
    const float* __restrict__ u, const float* __restrict__ w_ih,
    const float* __restrict__ w_hh, const float* __restrict__ b_ih,
    const float* __restrict__ b_hh, const float* __restrict__ head_w,
    const float* __restrict__ head_b, int* __restrict__ out) {
  const int lane = threadIdx.x & 63;
  const int rowA = blockIdx.x * 2;
  const int rowB = rowA + 1;

  __shared__ float hbA[NH];
  __shared__ float hbB[NH];

  // Per-lane weight rows: w_hh[(g*64+lane)][k], k = 0..63 (shared by A,B)
  float w_r[NH], w_z[NH], w_n[NH];
#pragma unroll
  for (int kq = 0; kq < 16; ++kq) {
    float4 a = *(const float4*)&w_hh[(size_t)(lane)*NH + kq * 4];
    float4 b = *(const float4*)&w_hh[(size_t)(64 + lane) * NH + kq * 4];
    float4 c = *(const float4*)&w_hh[(size_t)(128 + lane) * NH + kq * 4];
    w_r[kq * 4 + 0] = a.x; w_r[kq * 4 + 1] = a.y; w_r[kq * 4 + 2] = a.z; w_r[kq * 4 + 3] = a.w;
    w_z[kq * 4 + 0] = b.x; w_z[kq * 4 + 1] = b.y; w_z[kq * 4 + 2] = b.z; w_z[kq * 4 + 3] = b.w;
    w_n[kq * 4 + 0] = c.x; w_n[kq * 4 + 1] = c.y; w_n[kq * 4 + 2] = c.z; w_n[kq * 4 + 3] = c.w;
  }
  const float bih_r = b_ih[lane], bih_z = b_ih[64 + lane], bih_n = b_ih[128 + lane];
  const float bhh_r = b_hh[lane], bhh_z = b_hh[64 + lane], bhh_n = b_hh[128 + lane];
  // prev ∈ {0,1}: gx = prev*w_ih + b_ih == (prev ? w_ih+b_ih : b_ih) bit-exactly.
  const float sum_r = __fadd_rn(w_ih[lane], bih_r);
  const float sum_z = __fadd_rn(w_ih[64 + lane], bih_z);
  const float sum_n = __fadd_rn(w_ih[128 + lane], bih_n);
  const float hw = head_w[lane];
  const float hb = head_b[0];

  const float* urA = u + (size_t)rowA * NS;
  const float* urB = u + (size_t)rowB * NS;
  int* orA = out + (size_t)rowA * NS;
  int* orB = out + (size_t)rowB * NS;

  float hA = 0.0f, hB = 0.0f;
  int prevA = 0, prevB = 0;
  hbA[lane] = 0.0f;
  hbB[lane] = 0.0f;

  float uA_cur = urA[lane];
  float uB_cur = urB[lane];
  for (int c = 0; c < 16; ++c) {
    float uA_next = (c < 15) ? urA[(c + 1) * 64 + lane] : 0.0f;
    float uB_next = (c < 15) ? urB[(c + 1) * 64 + lane] : 0.0f;
    int mybitA = 0, mybitB = 0;
    for (int tt = 0; tt < 64; ++tt) {
      // gh = h @ w_hh.T for both rows: sequential-k FMA from 0 (Eigen gebp)
      float arA = 0.0f, azA = 0.0f, anA = 0.0f;
      float arB = 0.0f, azB = 0.0f, anB = 0.0f;
#pragma unroll
      for (int kq = 0; kq < 16; ++kq) {
        float4 hvA = *(const float4*)&hbA[kq * 4];
        float4 hvB = *(const float4*)&hbB[kq * 4];
        float w0 = w_r[kq * 4 + 0], w1 = w_r[kq * 4 + 1], w2 = w_r[kq * 4 + 2], w3 = w_r[kq * 4 + 3];
        arA = fmaf(hvA.x, w0, arA); arB = fmaf(hvB.x, w0, arB);
        arA = fmaf(hvA.y, w1, arA); arB = fmaf(hvB.y, w1, arB);
        arA = fmaf(hvA.z, w2, arA); arB = fmaf(hvB.z, w2, arB);
        arA = fmaf(hvA.w, w3, arA); arB = fmaf(hvB.w, w3, arB);
        w0 = w_z[kq * 4 + 0]; w1 = w_z[kq * 4 + 1]; w2 = w_z[kq * 4 + 2]; w3 = w_z[kq * 4 + 3];
        azA = fmaf(hvA.x, w0, azA); azB = fmaf(hvB.x, w0, azB);
        azA = fmaf(hvA.y, w1, azA); azB = fmaf(hvB.y, w1, azB);
        azA = fmaf(hvA.z, w2, azA); azB = fmaf(hvB.z, w2, azB);
        azA = fmaf(hvA.w, w3, azA); azB = fmaf(hvB.w, w3, azB);
        w0 = w_n[kq * 4 + 0]; w1 = w_n[kq * 4 + 1]; w2 = w_n[kq * 4 + 2]; w3 = w_n[kq * 4 + 3];
        anA = fmaf(hvA.x, w0, anA); anB = fmaf(hvB.x, w0, anB);
        anA = fmaf(hvA.y, w1, anA); anB = fmaf(hvB.y, w1, anB);
        anA = fmaf(hvA.z, w2, anA); anB = fmaf(hvB.z, w2, anB);
        anA = fmaf(hvA.w, w3, anA); anB = fmaf(hvB.w, w3, anB);
      }
      // gates, exact reference association
      float ghnA = __fadd_rn(anA, bhh_n);
      float ghnB = __fadd_rn(anB, bhh_n);
      float rA = xsigmoid(__fadd_rn(prevA ? sum_r : bih_r, __fadd_rn(arA, bhh_r)));
      float rB = xsigmoid(__fadd_rn(prevB ? sum_r : bih_r, __fadd_rn(arB, bhh_r)));
      float zA = xsigmoid(__fadd_rn(prevA ? sum_z : bih_z, __fadd_rn(azA, bhh_z)));
      float zB = xsigmoid(__fadd_rn(prevB ? sum_z : bih_z, __fadd_rn(azB, bhh_z)));
      float nA = xtanh(__fadd_rn(prevA ? sum_n : bih_n, __fmul_rn(rA, ghnA)));
      float nB = xtanh(__fadd_rn(prevB ? sum_n : bih_n, __fmul_rn(rB, ghnB)));
      hA = __fadd_rn(__fmul_rn(__fsub_rn(1.0f, zA), nA), __fmul_rn(zA, hA));
      hB = __fadd_rn(__fmul_rn(__fsub_rn(1.0f, zB), nB), __fmul_rn(zB, hB));
      hbA[lane] = hA;
      hbB[lane] = hB;

      // head gemv clone per row: width-16 chunks then halving tree
      float PA = __fmul_rn(hA, hw);
      float PB = __fmul_rn(hB, hw);
      float sA = __fadd_rn(PA, __shfl(PA, lane + 16));
      float sB = __fadd_rn(PB, __shfl(PB, lane + 16));
      sA = __fadd_rn(sA, __shfl(PA, lane + 32));
      sB = __fadd_rn(sB, __shfl(PB, lane + 32));
      sA = __fadd_rn(sA, __shfl(PA, lane + 48));
      sB = __fadd_rn(sB, __shfl(PB, lane + 48));
      sA = __fadd_rn(sA, __shfl(sA, lane + 8));
      sB = __fadd_rn(sB, __shfl(sB, lane + 8));
      sA = __fadd_rn(sA, __shfl(sA, lane + 4));
      sB = __fadd_rn(sB, __shfl(sB, lane + 4));
      sA = __fadd_rn(sA, __shfl(sA, lane + 2));
      sB = __fadd_rn(sB, __shfl(sB, lane + 2));
      sA = __fadd_rn(sA, __shfl(sA, lane + 1));
      sB = __fadd_rn(sB, __shfl(sB, lane + 1));
      float logitA = __fadd_rn(__shfl(sA, 0), hb);
      float logitB = __fadd_rn(__shfl(sB, 0), hb);

      // packed head sigmoid: one instruction stream serves both rows
      float lg = (lane < 32) ? logitA : logitB;
      float pp = xsigmoid(lg);
      float pA = __shfl(pp, 0);
      float pB = __shfl(pp, 32);

      float uAt = __shfl(uA_cur, tt);
      float uBt = __shfl(uB_cur, tt);
      int bA = (uAt < pA) ? 1 : 0;
      int bB = (uBt < pB) ? 1 : 0;
      prevA = bA;
      prevB = bB;
      mybitA = (lane == tt) ? bA : mybitA;
      mybitB = (lane == tt) ? bB : mybitB;
    }
    orA[c * 64 + lane] = mybitA;
    orB[c * 64 + lane] = mybitB;
    uA_cur = uA_next;
    uB_cur = uB_next;
  }
}

extern "C" void kernel_launch(void* const* d_in, const int* in_sizes, int n_in,
                              void* d_out, int out_size, void* d_ws, size_t ws_size,
                              hipStream_t stream) {
  const float* u = (const float*)d_in[0];
  const float* w_ih = (const float*)d_in[1];
  const float* w_hh = (const float*)d_in[2];
  const float* b_ih = (const float*)d_in[3];
  const float* b_hh = (const float*)d_in[4];
  const float* head_w = (const float*)d_in[5];
  const float* head_b = (const float*)d_in[6];
  int* out = (int*)d_out;
  dim3 grid(NB / 2), block(64);
  gru_sample_kernel<<<grid, block, 0, stream>>>(u, w_ih, w_hh, b_ih, b_hh,
                                                head_w, head_b, out);
}